// Round 17
// baseline (28.284 us; speedup 1.0000x reference)
//
#include <hip/hip_runtime.h>
#include <hip/hip_bf16.h>

#define NR 512
#define DF 576
#define LOG2E 1.4426950408889634f

#if __has_builtin(__builtin_amdgcn_exp2f)
#define EXP2F __builtin_amdgcn_exp2f
#else
#define EXP2F exp2f
#endif

typedef _Float16 f16x8 __attribute__((ext_vector_type(8)));
typedef float f32x4 __attribute__((ext_vector_type(4)));

// Workspace layout (bytes):
//  PTQ fp32 [kc(3)][512][576]  : 3,538,944  @ 0
//  PTK fp16 [kc(3)][512][576]  : 1,769,472  @ 3,538,944   (pre-scaled LOG2E)
//  PTV fp16 [kc(3)][512][576]  : 1,769,472  @ 5,308,416
#define PTQ_OFF 0
#define PTK_OFF 3538944
#define PTV_OFF 5308416

// ---------------------------------------------------------------------------
// Kernel 1: QKV GEMM with in-kernel fp32->fp16 conversion via LDS.
// (byte-identical to R16)
// ---------------------------------------------------------------------------
__global__ __launch_bounds__(256) void qkv_lds_kernel(
    const float* __restrict__ X,
    const float* __restrict__ Wq, const float* __restrict__ Wk,
    const float* __restrict__ Wv,
    float* __restrict__ PTQ, _Float16* __restrict__ PTK,
    _Float16* __restrict__ PTV)
{
    const int w  = blockIdx.z / 3;
    const int kc = blockIdx.z - w * 3;
    const float* W = (w == 0) ? Wq : (w == 1) ? Wk : Wv;

    const int tid  = threadIdx.x;
    const int lane = tid & 63;
    const int wv   = tid >> 6;
    const int rt   = wv >> 1;
    const int ct   = wv & 1;
    const int brow0 = blockIdx.y * 64;
    const int bcol0 = blockIdx.x * 64;
    const int kbase = kc * 192;

    __shared__ _Float16 LA[4 * 6 * 64 * 8];
    __shared__ _Float16 LB[4 * 6 * 64 * 8];

#pragma unroll
    for (int it = 0; it < 6; ++it) {
        const int task = it * 256 + tid;
        const int r  = task / 24;
        const int kq = task - r * 24;
        const int k  = kq * 8;

        const int fr   = r >> 4;
        const int ks   = k >> 5;
        const int lp   = (r & 15) + 16 * ((k & 31) >> 3);
        const int slot = lp ^ ks;
        _Float16* da = &LA[((fr * 6 + ks) * 64 + slot) * 8];
        _Float16* db = &LB[((fr * 6 + ks) * 64 + slot) * 8];

        {
            const float* s = X + (size_t)(brow0 + r) * DF + kbase + k;
            const float4 v0 = *reinterpret_cast<const float4*>(s);
            const float4 v1 = *reinterpret_cast<const float4*>(s + 4);
            f16x8 h = {(_Float16)v0.x, (_Float16)v0.y, (_Float16)v0.z, (_Float16)v0.w,
                       (_Float16)v1.x, (_Float16)v1.y, (_Float16)v1.z, (_Float16)v1.w};
            *reinterpret_cast<f16x8*>(da) = h;
        }
        {
            const float* s = W + (size_t)(bcol0 + r) * DF + kbase + k;
            const float4 v0 = *reinterpret_cast<const float4*>(s);
            const float4 v1 = *reinterpret_cast<const float4*>(s + 4);
            f16x8 h = {(_Float16)v0.x, (_Float16)v0.y, (_Float16)v0.z, (_Float16)v0.w,
                       (_Float16)v1.x, (_Float16)v1.y, (_Float16)v1.z, (_Float16)v1.w};
            *reinterpret_cast<f16x8*>(db) = h;
        }
    }
    __syncthreads();

    f32x4 acc[2][2] = {{{0.f,0.f,0.f,0.f},{0.f,0.f,0.f,0.f}},
                       {{0.f,0.f,0.f,0.f},{0.f,0.f,0.f,0.f}}};
#pragma unroll
    for (int half = 0; half < 2; ++half) {
        f16x8 fa[2][3], fb[2][3];
#pragma unroll
        for (int s = 0; s < 3; ++s) {
            const int ks = half * 3 + s;
            const int sl = (lane ^ ks) * 8;
#pragma unroll
            for (int mi = 0; mi < 2; ++mi)
                fa[mi][s] = *reinterpret_cast<const f16x8*>(
                    &LA[((rt * 2 + mi) * 6 + ks) * 512 + sl]);
#pragma unroll
            for (int ni = 0; ni < 2; ++ni)
                fb[ni][s] = *reinterpret_cast<const f16x8*>(
                    &LB[((ct * 2 + ni) * 6 + ks) * 512 + sl]);
        }
#pragma unroll
        for (int s = 0; s < 3; ++s) {
            acc[0][0] = __builtin_amdgcn_mfma_f32_16x16x32_f16(fa[0][s], fb[0][s], acc[0][0], 0, 0, 0);
            acc[0][1] = __builtin_amdgcn_mfma_f32_16x16x32_f16(fa[0][s], fb[1][s], acc[0][1], 0, 0, 0);
            acc[1][0] = __builtin_amdgcn_mfma_f32_16x16x32_f16(fa[1][s], fb[0][s], acc[1][0], 0, 0, 0);
            acc[1][1] = __builtin_amdgcn_mfma_f32_16x16x32_f16(fa[1][s], fb[1][s], acc[1][1], 0, 0, 0);
        }
    }

    const size_t pl = (size_t)NR * DF;
#pragma unroll
    for (int ni = 0; ni < 2; ++ni) {
        const int col = bcol0 + ct * 32 + ni * 16 + (lane & 15);
#pragma unroll
        for (int mi = 0; mi < 2; ++mi) {
            const int row0 = brow0 + rt * 32 + mi * 16 + (lane >> 4) * 4;
#pragma unroll
            for (int r = 0; r < 4; ++r) {
                const size_t idx = kc * pl + (size_t)(row0 + r) * DF + col;
                const float v = acc[mi][ni][r];
                if (w == 0)      PTQ[idx] = v;
                else if (w == 1) PTK[idx] = (_Float16)(v * LOG2E);
                else             PTV[idx] = (_Float16)v;
            }
        }
    }
}

// ---------------------------------------------------------------------------
// Kernel 2: rank-1 attention (byte-identical to R16).
// ---------------------------------------------------------------------------
#define M_NODES 36
#define CHUNKS  16
#define JPC     36
#define CSTRIDE 19

__global__ __launch_bounds__(576) void attn_interp_kernel(
    const float* __restrict__ PTQ, const _Float16* __restrict__ PTK,
    const _Float16* __restrict__ PTV,
    const float* __restrict__ bq, const float* __restrict__ bk,
    const float* __restrict__ bv,
    float* __restrict__ out)
{
    const int n = blockIdx.x;
    const int t = threadIdx.x;
    const size_t nb = (size_t)n * DF + t;
    const size_t pl = (size_t)NR * DF;

    const float qv = ((PTQ[nb] + PTQ[pl + nb]) + PTQ[pl * 2 + nb]) + bq[t];
    const float kl = ((float)PTK[nb] + (float)PTK[pl + nb] + (float)PTK[pl * 2 + nb])
                     + bk[t] * LOG2E;
    const float vv = ((float)PTV[nb] + (float)PTV[pl + nb] + (float)PTV[pl * 2 + nb])
                     + bv[t];

    __shared__ __align__(16) float4 KV4[CHUNKS * CSTRIDE];
    __shared__ __align__(16) float Pf[DF];
    __shared__ __align__(16) float Pg[DF];
    __shared__ float Rt[M_NODES];
    __shared__ float range[2];

    {
        const int c  = t / JPC;
        const int jl = t - c * JPC;
        float2* dst = reinterpret_cast<float2*>(&KV4[c * CSTRIDE + (jl >> 1)]);
        dst[jl & 1] = make_float2(kl, vv);
    }
    Pf[t] = qv;
    __syncthreads();

    if (t < 64) {
        float lo = Pf[t], hi = lo;
#pragma unroll
        for (int r = 1; r < 9; ++r) {
            float v = Pf[t + 64 * r];
            lo = fminf(lo, v); hi = fmaxf(hi, v);
        }
#pragma unroll
        for (int s = 32; s; s >>= 1) {
            lo = fminf(lo, __shfl_xor(lo, s, 64));
            hi = fmaxf(hi, __shfl_xor(hi, s, 64));
        }
        if (t == 0) { range[0] = lo; range[1] = hi; }
    }
    __syncthreads();

    const float qmin = range[0], qmax = range[1];
    const float h    = fmaxf((qmax - qmin) * (1.0f / (M_NODES - 5)), 1e-6f);
    const float qlo  = qmin - 2.0f * h;

    const int m = t >> 4;
    const int c = t & 15;
    const float qm = qlo + h * (float)m;
    const float4* kvp = KV4 + c * CSTRIDE;
    float f0 = 0.f, f1 = 0.f, g0 = 0.f, g1 = 0.f;
#pragma unroll
    for (int jj = 0; jj < JPC / 2; ++jj) {
        float4 p = kvp[jj];
        float e0 = EXP2F(qm * p.x);
        float e1 = EXP2F(qm * p.z);
        g0 += e0; g1 += e1;
        f0 = fmaf(e0, p.y, f0);
        f1 = fmaf(e1, p.w, f1);
    }
    __syncthreads();
    Pf[t] = f0 + f1;
    Pg[t] = g0 + g1;
    __syncthreads();

    if (t < M_NODES) {
        const float4* pf4 = reinterpret_cast<const float4*>(Pf) + t * 4;
        const float4* pg4 = reinterpret_cast<const float4*>(Pg) + t * 4;
        float fs = 0.f, gs = 0.f;
#pragma unroll
        for (int i = 0; i < 4; ++i) {
            float4 a = pf4[i], b = pg4[i];
            fs += (a.x + a.y) + (a.z + a.w);
            gs += (b.x + b.y) + (b.z + b.w);
        }
        Rt[t] = fs / gs;
    }
    __syncthreads();

    const float u = (qv - qlo) * (1.0f / h);
    int i0 = (int)u;
    i0 = (i0 < 1) ? 1 : (i0 > M_NODES - 3 ? M_NODES - 3 : i0);
    const float tf = u - (float)i0;
    const float a  = Rt[i0 - 1];
    const float b  = Rt[i0];
    const float cc = Rt[i0 + 1];
    const float d  = Rt[i0 + 2];
    const float m0 = 0.5f * (cc - a);
    const float m1 = 0.5f * (d - b);
    const float dd = cc - b;
    const float r  = b + tf * (m0 + tf * ((3.f * dd - 2.f * m0 - m1)
                                          + tf * (m0 + m1 - 2.f * dd)));
    out[(size_t)n * DF + t] = r;
}

// ---------------------------------------------------------------------------
extern "C" void kernel_launch(void* const* d_in, const int* in_sizes, int n_in,
                              void* d_out, int out_size, void* d_ws, size_t ws_size,
                              hipStream_t stream) {
    const float* x  = (const float*)d_in[0];
    const float* Wq = (const float*)d_in[1];
    const float* bq = (const float*)d_in[2];
    const float* Wk = (const float*)d_in[3];
    const float* bk = (const float*)d_in[4];
    const float* Wv = (const float*)d_in[5];
    const float* bv = (const float*)d_in[6];

    char* ws = (char*)d_ws;
    float*     PTQ = (float*)(ws + PTQ_OFF);
    _Float16*  PTK = (_Float16*)(ws + PTK_OFF);
    _Float16*  PTV = (_Float16*)(ws + PTV_OFF);

    // MEASUREMENT PROBE: gemm launched twice (idempotent, deterministic).
    // T_this = 2*gemm + attn + 2 boundaries; T_prev = gemm + attn + 1.
    // Delta = gemm + boundary -> decides endgame allocation.
    qkv_lds_kernel<<<dim3(9, 8, 9), 256, 0, stream>>>(
        x, Wq, Wk, Wv, PTQ, PTK, PTV);
    qkv_lds_kernel<<<dim3(9, 8, 9), 256, 0, stream>>>(
        x, Wq, Wk, Wv, PTQ, PTK, PTV);

    attn_interp_kernel<<<NR, DF, 0, stream>>>(
        PTQ, PTK, PTV, bq, bk, bv, (float*)d_out);
}

// Round 18
// 17.832 us; speedup vs baseline: 1.5861x; 1.5861x over previous
//
#include <hip/hip_runtime.h>
#include <hip/hip_bf16.h>

#define NR 512
#define DF 576
#define LOG2E 1.4426950408889634f

#if __has_builtin(__builtin_amdgcn_exp2f)
#define EXP2F __builtin_amdgcn_exp2f
#else
#define EXP2F exp2f
#endif

typedef _Float16 f16x8 __attribute__((ext_vector_type(8)));
typedef float f32x4 __attribute__((ext_vector_type(4)));

// Workspace layout (bytes):
//  PTQ fp32 [kc(3)][512][576]  : 3,538,944  @ 0
//  PTK fp16 [kc(3)][512][576]  : 1,769,472  @ 3,538,944   (pre-scaled LOG2E)
//  PTV fp16 [kc(3)][512][576]  : 1,769,472  @ 5,308,416
#define PTQ_OFF 0
#define PTK_OFF 3538944
#define PTV_OFF 5308416

// ---------------------------------------------------------------------------
// Kernel 1: QKV GEMM, BM=128 x BN=64, in-kernel fp32->fp16 via LDS.
// Grid (9,4,9): x=colt(64 cols), y=rowt(128 rows), z=w*3+kc (K-chunk 192).
// 512 thr = 8 waves (4x2).  W panel amortized over 128 rows: total fp32
// read traffic 47.8 MB (vs 63.7 at BM=64).  LDS 72 KB -> 2 blocks/CU.
// ---------------------------------------------------------------------------
__global__ __launch_bounds__(512) void qkv_lds_kernel(
    const float* __restrict__ X,
    const float* __restrict__ Wq, const float* __restrict__ Wk,
    const float* __restrict__ Wv,
    float* __restrict__ PTQ, _Float16* __restrict__ PTK,
    _Float16* __restrict__ PTV)
{
    const int w  = blockIdx.z / 3;
    const int kc = blockIdx.z - w * 3;
    const float* W = (w == 0) ? Wq : (w == 1) ? Wk : Wv;

    const int tid  = threadIdx.x;
    const int lane = tid & 63;
    const int wv   = tid >> 6;           // 0..7
    const int wr   = wv >> 1;            // 0..3  (32-row tile within 128)
    const int wc   = wv & 1;             // 0..1  (32-col tile within 64)
    const int brow0 = blockIdx.y * 128;
    const int bcol0 = blockIdx.x * 64;
    const int kbase = kc * 192;

    __shared__ _Float16 LA[8 * 6 * 64 * 8];   // 48 KB  [fr][ks][slot][8]
    __shared__ _Float16 LB[4 * 6 * 64 * 8];   // 24 KB

    // ---- stage A: X[128x192] -> frag-ordered LDS (6 iters) ----
#pragma unroll
    for (int it = 0; it < 6; ++it) {
        const int task = it * 512 + tid;       // 0..3071
        const int r  = task / 24;              // 0..127
        const int kq = task - r * 24;
        const int k  = kq * 8;
        const int fr   = r >> 4;
        const int ks   = k >> 5;
        const int slot = ((r & 15) + 16 * ((k & 31) >> 3)) ^ ks;
        const float* s = X + (size_t)(brow0 + r) * DF + kbase + k;
        const float4 v0 = *reinterpret_cast<const float4*>(s);
        const float4 v1 = *reinterpret_cast<const float4*>(s + 4);
        f16x8 h = {(_Float16)v0.x, (_Float16)v0.y, (_Float16)v0.z, (_Float16)v0.w,
                   (_Float16)v1.x, (_Float16)v1.y, (_Float16)v1.z, (_Float16)v1.w};
        *reinterpret_cast<f16x8*>(&LA[((fr * 6 + ks) * 64 + slot) * 8]) = h;
    }
    // ---- stage B: W[64x192] -> frag-ordered LDS (3 iters) ----
#pragma unroll
    for (int it = 0; it < 3; ++it) {
        const int task = it * 512 + tid;       // 0..1535
        const int r  = task / 24;              // 0..63
        const int kq = task - r * 24;
        const int k  = kq * 8;
        const int fr   = r >> 4;
        const int ks   = k >> 5;
        const int slot = ((r & 15) + 16 * ((k & 31) >> 3)) ^ ks;
        const float* s = W + (size_t)(bcol0 + r) * DF + kbase + k;
        const float4 v0 = *reinterpret_cast<const float4*>(s);
        const float4 v1 = *reinterpret_cast<const float4*>(s + 4);
        f16x8 h = {(_Float16)v0.x, (_Float16)v0.y, (_Float16)v0.z, (_Float16)v0.w,
                   (_Float16)v1.x, (_Float16)v1.y, (_Float16)v1.z, (_Float16)v1.w};
        *reinterpret_cast<f16x8*>(&LB[((fr * 6 + ks) * 64 + slot) * 8]) = h;
    }
    __syncthreads();

    // ---- MFMA from LDS: per wave 2x2 frags over 6 k-slices ----
    f32x4 acc[2][2] = {{{0.f,0.f,0.f,0.f},{0.f,0.f,0.f,0.f}},
                       {{0.f,0.f,0.f,0.f},{0.f,0.f,0.f,0.f}}};
#pragma unroll
    for (int half = 0; half < 2; ++half) {
        f16x8 fa[2][3], fb[2][3];
#pragma unroll
        for (int s = 0; s < 3; ++s) {
            const int ks = half * 3 + s;
            const int sl = (lane ^ ks) * 8;
#pragma unroll
            for (int mi = 0; mi < 2; ++mi)
                fa[mi][s] = *reinterpret_cast<const f16x8*>(
                    &LA[((wr * 2 + mi) * 6 + ks) * 512 + sl]);
#pragma unroll
            for (int ni = 0; ni < 2; ++ni)
                fb[ni][s] = *reinterpret_cast<const f16x8*>(
                    &LB[((wc * 2 + ni) * 6 + ks) * 512 + sl]);
        }
#pragma unroll
        for (int s = 0; s < 3; ++s) {
            acc[0][0] = __builtin_amdgcn_mfma_f32_16x16x32_f16(fa[0][s], fb[0][s], acc[0][0], 0, 0, 0);
            acc[0][1] = __builtin_amdgcn_mfma_f32_16x16x32_f16(fa[0][s], fb[1][s], acc[0][1], 0, 0, 0);
            acc[1][0] = __builtin_amdgcn_mfma_f32_16x16x32_f16(fa[1][s], fb[0][s], acc[1][0], 0, 0, 0);
            acc[1][1] = __builtin_amdgcn_mfma_f32_16x16x32_f16(fa[1][s], fb[1][s], acc[1][1], 0, 0, 0);
        }
    }

    // ---- epilogue ----
    const size_t pl = (size_t)NR * DF;
#pragma unroll
    for (int ni = 0; ni < 2; ++ni) {
        const int col = bcol0 + wc * 32 + ni * 16 + (lane & 15);
#pragma unroll
        for (int mi = 0; mi < 2; ++mi) {
            const int row0 = brow0 + wr * 32 + mi * 16 + (lane >> 4) * 4;
#pragma unroll
            for (int r = 0; r < 4; ++r) {
                const size_t idx = kc * pl + (size_t)(row0 + r) * DF + col;
                const float v = acc[mi][ni][r];
                if (w == 0)      PTQ[idx] = v;
                else if (w == 1) PTK[idx] = (_Float16)(v * LOG2E);
                else             PTV[idx] = (_Float16)v;
            }
        }
    }
}

// ---------------------------------------------------------------------------
// Kernel 2: rank-1 attention via tilted-mean interpolation.
// 24 nodes x 24 chunks (576 = 24*24): 24 exps + 12 float4 LDS reads per
// thread in the build (was 36 + 18).  Fused 3-way split-K reduce (+bias).
// ---------------------------------------------------------------------------
#define M_NODES 24
#define CHUNKS  24
#define JPC     24
#define CSTRIDE 13            // float4 units: 12 data + 1 pad

__global__ __launch_bounds__(576) void attn_interp_kernel(
    const float* __restrict__ PTQ, const _Float16* __restrict__ PTK,
    const _Float16* __restrict__ PTV,
    const float* __restrict__ bq, const float* __restrict__ bk,
    const float* __restrict__ bv,
    float* __restrict__ out)
{
    const int n = blockIdx.x;
    const int t = threadIdx.x;
    const size_t nb = (size_t)n * DF + t;
    const size_t pl = (size_t)NR * DF;

    const float qv = ((PTQ[nb] + PTQ[pl + nb]) + PTQ[pl * 2 + nb]) + bq[t];
    const float kl = ((float)PTK[nb] + (float)PTK[pl + nb] + (float)PTK[pl * 2 + nb])
                     + bk[t] * LOG2E;
    const float vv = ((float)PTV[nb] + (float)PTV[pl + nb] + (float)PTV[pl * 2 + nb])
                     + bv[t];

    __shared__ __align__(16) float4 KV4[CHUNKS * CSTRIDE];   // 4992 B
    __shared__ __align__(16) float Pf[DF];
    __shared__ __align__(16) float Pg[DF];
    __shared__ float Rt[M_NODES];
    __shared__ float range[2];

    {
        const int c  = t / JPC;
        const int jl = t - c * JPC;
        float2* dst = reinterpret_cast<float2*>(&KV4[c * CSTRIDE + (jl >> 1)]);
        dst[jl & 1] = make_float2(kl, vv);
    }
    Pf[t] = qv;
    __syncthreads();

    if (t < 64) {
        float lo = Pf[t], hi = lo;
#pragma unroll
        for (int r = 1; r < 9; ++r) {
            float v = Pf[t + 64 * r];
            lo = fminf(lo, v); hi = fmaxf(hi, v);
        }
#pragma unroll
        for (int s = 32; s; s >>= 1) {
            lo = fminf(lo, __shfl_xor(lo, s, 64));
            hi = fmaxf(hi, __shfl_xor(hi, s, 64));
        }
        if (t == 0) { range[0] = lo; range[1] = hi; }
    }
    __syncthreads();

    const float qmin = range[0], qmax = range[1];
    const float h    = fmaxf((qmax - qmin) * (1.0f / (M_NODES - 5)), 1e-6f);
    const float qlo  = qmin - 2.0f * h;

    // build: thread = (node m, chunk c); 24 j's each
    const int m = t / CHUNKS;
    const int c = t - m * CHUNKS;
    const float qm = qlo + h * (float)m;
    const float4* kvp = KV4 + c * CSTRIDE;
    float f0 = 0.f, f1 = 0.f, g0 = 0.f, g1 = 0.f;
#pragma unroll
    for (int jj = 0; jj < JPC / 2; ++jj) {
        float4 p = kvp[jj];
        float e0 = EXP2F(qm * p.x);
        float e1 = EXP2F(qm * p.z);
        g0 += e0; g1 += e1;
        f0 = fmaf(e0, p.y, f0);
        f1 = fmaf(e1, p.w, f1);
    }
    __syncthreads();
    Pf[t] = f0 + f1;
    Pg[t] = g0 + g1;
    __syncthreads();

    if (t < M_NODES) {                   // reduce 24 chunks -> R node
        const float4* pf4 = reinterpret_cast<const float4*>(Pf) + t * 6;
        const float4* pg4 = reinterpret_cast<const float4*>(Pg) + t * 6;
        float fs = 0.f, gs = 0.f;
#pragma unroll
        for (int i = 0; i < 6; ++i) {
            float4 a = pf4[i], b = pg4[i];
            fs += (a.x + a.y) + (a.z + a.w);
            gs += (b.x + b.y) + (b.z + b.w);
        }
        Rt[t] = fs / gs;
    }
    __syncthreads();

    const float u = (qv - qlo) * (1.0f / h);
    int i0 = (int)u;
    i0 = (i0 < 1) ? 1 : (i0 > M_NODES - 3 ? M_NODES - 3 : i0);
    const float tf = u - (float)i0;
    const float a  = Rt[i0 - 1];
    const float b  = Rt[i0];
    const float cc = Rt[i0 + 1];
    const float d  = Rt[i0 + 2];
    const float m0 = 0.5f * (cc - a);
    const float m1 = 0.5f * (d - b);
    const float dd = cc - b;
    const float r  = b + tf * (m0 + tf * ((3.f * dd - 2.f * m0 - m1)
                                          + tf * (m0 + m1 - 2.f * dd)));
    out[(size_t)n * DF + t] = r;
}

// ---------------------------------------------------------------------------
extern "C" void kernel_launch(void* const* d_in, const int* in_sizes, int n_in,
                              void* d_out, int out_size, void* d_ws, size_t ws_size,
                              hipStream_t stream) {
    const float* x  = (const float*)d_in[0];
    const float* Wq = (const float*)d_in[1];
    const float* bq = (const float*)d_in[2];
    const float* Wk = (const float*)d_in[3];
    const float* bk = (const float*)d_in[4];
    const float* Wv = (const float*)d_in[5];
    const float* bv = (const float*)d_in[6];

    char* ws = (char*)d_ws;
    float*     PTQ = (float*)(ws + PTQ_OFF);
    _Float16*  PTK = (_Float16*)(ws + PTK_OFF);
    _Float16*  PTV = (_Float16*)(ws + PTV_OFF);

    qkv_lds_kernel<<<dim3(9, 4, 9), 512, 0, stream>>>(
        x, Wq, Wk, Wv, PTQ, PTK, PTV);

    attn_interp_kernel<<<NR, DF, 0, stream>>>(
        PTQ, PTK, PTV, bq, bk, bv, (float*)d_out);
}

// Round 19
// 16.904 us; speedup vs baseline: 1.6732x; 1.0549x over previous
//
#include <hip/hip_runtime.h>
#include <hip/hip_bf16.h>

#define NR 512
#define DF 576
#define LOG2E 1.4426950408889634f

#if __has_builtin(__builtin_amdgcn_exp2f)
#define EXP2F __builtin_amdgcn_exp2f
#else
#define EXP2F exp2f
#endif

typedef _Float16 f16x8 __attribute__((ext_vector_type(8)));
typedef float f32x4 __attribute__((ext_vector_type(4)));

// Workspace layout (bytes):
//  PTQ fp16 [kc(3)][512][576] : 1,769,472 @ 0
//  PTK fp16 [kc(3)][512][576] : 1,769,472 @ 1,769,472   (pre-scaled LOG2E)
//  PTV fp16 [kc(3)][512][576] : 1,769,472 @ 3,538,944
#define PTQ_OFF 0
#define PTK_OFF 1769472
#define PTV_OFF 3538944

// ---------------------------------------------------------------------------
// Kernel 1: QKV GEMM, BM=128 x BN=64, in-kernel fp32->fp16 via LDS.
// Grid (9,4,9): x=colt(64 cols), y=rowt(128 rows), z=w*3+kc (K-chunk 192).
// 512 thr = 8 waves (4x2).  47.8 MB fp32 read traffic.  All partials fp16
// now (PT total 5.3 MB -> smaller boundary flush + attn reads).
// ---------------------------------------------------------------------------
__global__ __launch_bounds__(512) void qkv_lds_kernel(
    const float* __restrict__ X,
    const float* __restrict__ Wq, const float* __restrict__ Wk,
    const float* __restrict__ Wv,
    _Float16* __restrict__ PTQ, _Float16* __restrict__ PTK,
    _Float16* __restrict__ PTV)
{
    const int w  = blockIdx.z / 3;
    const int kc = blockIdx.z - w * 3;
    const float* W = (w == 0) ? Wq : (w == 1) ? Wk : Wv;

    const int tid  = threadIdx.x;
    const int lane = tid & 63;
    const int wv   = tid >> 6;           // 0..7
    const int wr   = wv >> 1;            // 0..3
    const int wc   = wv & 1;             // 0..1
    const int brow0 = blockIdx.y * 128;
    const int bcol0 = blockIdx.x * 64;
    const int kbase = kc * 192;

    __shared__ _Float16 LA[8 * 6 * 64 * 8];   // 48 KB  [fr][ks][slot][8]
    __shared__ _Float16 LB[4 * 6 * 64 * 8];   // 24 KB

#pragma unroll
    for (int it = 0; it < 6; ++it) {
        const int task = it * 512 + tid;
        const int r  = task / 24;
        const int kq = task - r * 24;
        const int k  = kq * 8;
        const int fr   = r >> 4;
        const int ks   = k >> 5;
        const int slot = ((r & 15) + 16 * ((k & 31) >> 3)) ^ ks;
        const float* s = X + (size_t)(brow0 + r) * DF + kbase + k;
        const float4 v0 = *reinterpret_cast<const float4*>(s);
        const float4 v1 = *reinterpret_cast<const float4*>(s + 4);
        f16x8 h = {(_Float16)v0.x, (_Float16)v0.y, (_Float16)v0.z, (_Float16)v0.w,
                   (_Float16)v1.x, (_Float16)v1.y, (_Float16)v1.z, (_Float16)v1.w};
        *reinterpret_cast<f16x8*>(&LA[((fr * 6 + ks) * 64 + slot) * 8]) = h;
    }
#pragma unroll
    for (int it = 0; it < 3; ++it) {
        const int task = it * 512 + tid;
        const int r  = task / 24;
        const int kq = task - r * 24;
        const int k  = kq * 8;
        const int fr   = r >> 4;
        const int ks   = k >> 5;
        const int slot = ((r & 15) + 16 * ((k & 31) >> 3)) ^ ks;
        const float* s = W + (size_t)(bcol0 + r) * DF + kbase + k;
        const float4 v0 = *reinterpret_cast<const float4*>(s);
        const float4 v1 = *reinterpret_cast<const float4*>(s + 4);
        f16x8 h = {(_Float16)v0.x, (_Float16)v0.y, (_Float16)v0.z, (_Float16)v0.w,
                   (_Float16)v1.x, (_Float16)v1.y, (_Float16)v1.z, (_Float16)v1.w};
        *reinterpret_cast<f16x8*>(&LB[((fr * 6 + ks) * 64 + slot) * 8]) = h;
    }
    __syncthreads();

    f32x4 acc[2][2] = {{{0.f,0.f,0.f,0.f},{0.f,0.f,0.f,0.f}},
                       {{0.f,0.f,0.f,0.f},{0.f,0.f,0.f,0.f}}};
#pragma unroll
    for (int half = 0; half < 2; ++half) {
        f16x8 fa[2][3], fb[2][3];
#pragma unroll
        for (int s = 0; s < 3; ++s) {
            const int ks = half * 3 + s;
            const int sl = (lane ^ ks) * 8;
#pragma unroll
            for (int mi = 0; mi < 2; ++mi)
                fa[mi][s] = *reinterpret_cast<const f16x8*>(
                    &LA[((wr * 2 + mi) * 6 + ks) * 512 + sl]);
#pragma unroll
            for (int ni = 0; ni < 2; ++ni)
                fb[ni][s] = *reinterpret_cast<const f16x8*>(
                    &LB[((wc * 2 + ni) * 6 + ks) * 512 + sl]);
        }
#pragma unroll
        for (int s = 0; s < 3; ++s) {
            acc[0][0] = __builtin_amdgcn_mfma_f32_16x16x32_f16(fa[0][s], fb[0][s], acc[0][0], 0, 0, 0);
            acc[0][1] = __builtin_amdgcn_mfma_f32_16x16x32_f16(fa[0][s], fb[1][s], acc[0][1], 0, 0, 0);
            acc[1][0] = __builtin_amdgcn_mfma_f32_16x16x32_f16(fa[1][s], fb[0][s], acc[1][0], 0, 0, 0);
            acc[1][1] = __builtin_amdgcn_mfma_f32_16x16x32_f16(fa[1][s], fb[1][s], acc[1][1], 0, 0, 0);
        }
    }

    const size_t pl = (size_t)NR * DF;
#pragma unroll
    for (int ni = 0; ni < 2; ++ni) {
        const int col = bcol0 + wc * 32 + ni * 16 + (lane & 15);
#pragma unroll
        for (int mi = 0; mi < 2; ++mi) {
            const int row0 = brow0 + wr * 32 + mi * 16 + (lane >> 4) * 4;
#pragma unroll
            for (int r = 0; r < 4; ++r) {
                const size_t idx = kc * pl + (size_t)(row0 + r) * DF + col;
                const float v = acc[mi][ni][r];
                if (w == 0)      PTQ[idx] = (_Float16)v;
                else if (w == 1) PTK[idx] = (_Float16)(v * LOG2E);
                else             PTV[idx] = (_Float16)v;
            }
        }
    }
}

// ---------------------------------------------------------------------------
// Kernel 2: rank-1 attention via tilted-mean interpolation.
// 24 nodes x 24 chunks.  Fused 3-way split-K reduce (+bias), all-fp16
// partials.  Wave-parallel q min/max (9 waves shfl-reduce, LDS broadcast).
// ---------------------------------------------------------------------------
#define M_NODES 24
#define CHUNKS  24
#define JPC     24
#define CSTRIDE 13            // float4 units: 12 data + 1 pad

__global__ __launch_bounds__(576) void attn_interp_kernel(
    const _Float16* __restrict__ PTQ, const _Float16* __restrict__ PTK,
    const _Float16* __restrict__ PTV,
    const float* __restrict__ bq, const float* __restrict__ bk,
    const float* __restrict__ bv,
    float* __restrict__ out)
{
    const int n = blockIdx.x;
    const int t = threadIdx.x;
    const size_t nb = (size_t)n * DF + t;
    const size_t pl = (size_t)NR * DF;

    const float qv = ((float)PTQ[nb] + (float)PTQ[pl + nb] + (float)PTQ[pl * 2 + nb])
                     + bq[t];
    const float kl = ((float)PTK[nb] + (float)PTK[pl + nb] + (float)PTK[pl * 2 + nb])
                     + bk[t] * LOG2E;
    const float vv = ((float)PTV[nb] + (float)PTV[pl + nb] + (float)PTV[pl * 2 + nb])
                     + bv[t];

    __shared__ __align__(16) float4 KV4[CHUNKS * CSTRIDE];   // 4992 B
    __shared__ __align__(16) float Pf[DF];
    __shared__ __align__(16) float Pg[DF];
    __shared__ float Rt[M_NODES];
    __shared__ float Wmn[9], Wmx[9];

    {
        const int c  = t / JPC;
        const int jl = t - c * JPC;
        float2* dst = reinterpret_cast<float2*>(&KV4[c * CSTRIDE + (jl >> 1)]);
        dst[jl & 1] = make_float2(kl, vv);
    }

    // wave-parallel min/max of q (9 waves in parallel, then LDS broadcast)
    {
        float lo = qv, hi = qv;
#pragma unroll
        for (int s = 32; s; s >>= 1) {
            lo = fminf(lo, __shfl_xor(lo, s, 64));
            hi = fmaxf(hi, __shfl_xor(hi, s, 64));
        }
        if ((t & 63) == 0) { Wmn[t >> 6] = lo; Wmx[t >> 6] = hi; }
    }
    __syncthreads();            // covers KV4 staging + Wmn/Wmx

    float qmin = Wmn[0], qmax = Wmx[0];
#pragma unroll
    for (int i = 1; i < 9; ++i) {
        qmin = fminf(qmin, Wmn[i]);
        qmax = fmaxf(qmax, Wmx[i]);
    }
    const float h   = fmaxf((qmax - qmin) * (1.0f / (M_NODES - 5)), 1e-6f);
    const float qlo = qmin - 2.0f * h;

    // build: thread = (node m, chunk c); 24 j's each
    const int m = t / CHUNKS;
    const int c = t - m * CHUNKS;
    const float qm = qlo + h * (float)m;
    const float4* kvp = KV4 + c * CSTRIDE;
    float f0 = 0.f, f1 = 0.f, g0 = 0.f, g1 = 0.f;
#pragma unroll
    for (int jj = 0; jj < JPC / 2; ++jj) {
        float4 p = kvp[jj];
        float e0 = EXP2F(qm * p.x);
        float e1 = EXP2F(qm * p.z);
        g0 += e0; g1 += e1;
        f0 = fmaf(e0, p.y, f0);
        f1 = fmaf(e1, p.w, f1);
    }
    Pf[t] = f0 + f1;
    Pg[t] = g0 + g1;
    __syncthreads();

    if (t < M_NODES) {                   // reduce 24 chunks -> R node
        const float4* pf4 = reinterpret_cast<const float4*>(Pf) + t * 6;
        const float4* pg4 = reinterpret_cast<const float4*>(Pg) + t * 6;
        float fs = 0.f, gs = 0.f;
#pragma unroll
        for (int i = 0; i < 6; ++i) {
            float4 a = pf4[i], b = pg4[i];
            fs += (a.x + a.y) + (a.z + a.w);
            gs += (b.x + b.y) + (b.z + b.w);
        }
        Rt[t] = fs / gs;
    }
    __syncthreads();

    const float u = (qv - qlo) * (1.0f / h);
    int i0 = (int)u;
    i0 = (i0 < 1) ? 1 : (i0 > M_NODES - 3 ? M_NODES - 3 : i0);
    const float tf = u - (float)i0;
    const float a  = Rt[i0 - 1];
    const float b  = Rt[i0];
    const float cc = Rt[i0 + 1];
    const float d  = Rt[i0 + 2];
    const float m0 = 0.5f * (cc - a);
    const float m1 = 0.5f * (d - b);
    const float dd = cc - b;
    const float r  = b + tf * (m0 + tf * ((3.f * dd - 2.f * m0 - m1)
                                          + tf * (m0 + m1 - 2.f * dd)));
    out[(size_t)n * DF + t] = r;
}

// ---------------------------------------------------------------------------
extern "C" void kernel_launch(void* const* d_in, const int* in_sizes, int n_in,
                              void* d_out, int out_size, void* d_ws, size_t ws_size,
                              hipStream_t stream) {
    const float* x  = (const float*)d_in[0];
    const float* Wq = (const float*)d_in[1];
    const float* bq = (const float*)d_in[2];
    const float* Wk = (const float*)d_in[3];
    const float* bk = (const float*)d_in[4];
    const float* Wv = (const float*)d_in[5];
    const float* bv = (const float*)d_in[6];

    char* ws = (char*)d_ws;
    _Float16* PTQ = (_Float16*)(ws + PTQ_OFF);
    _Float16* PTK = (_Float16*)(ws + PTK_OFF);
    _Float16* PTV = (_Float16*)(ws + PTV_OFF);

    qkv_lds_kernel<<<dim3(9, 4, 9), 512, 0, stream>>>(
        x, Wq, Wk, Wv, PTQ, PTK, PTV);

    attn_interp_kernel<<<NR, DF, 0, stream>>>(
        PTQ, PTK, PTV, bq, bk, bv, (float*)d_out);
}

// Round 20
// 16.834 us; speedup vs baseline: 1.6802x; 1.0042x over previous
//
#include <hip/hip_runtime.h>
#include <hip/hip_bf16.h>

#define NR 512
#define DF 576
#define LOG2E 1.4426950408889634f

#if __has_builtin(__builtin_amdgcn_exp2f)
#define EXP2F __builtin_amdgcn_exp2f
#else
#define EXP2F exp2f
#endif

typedef _Float16 f16x8 __attribute__((ext_vector_type(8)));
typedef float f32x4 __attribute__((ext_vector_type(4)));

// Workspace layout (bytes):
//  PTQ fp16 [kc(3)][512][576] : 1,769,472 @ 0
//  PTK fp16 [kc(3)][512][576] : 1,769,472 @ 1,769,472   (pre-scaled LOG2E)
//  PTV fp16 [kc(3)][512][576] : 1,769,472 @ 3,538,944
#define PTQ_OFF 0
#define PTK_OFF 1769472
#define PTV_OFF 3538944

// ---------------------------------------------------------------------------
// Kernel 1: QKV GEMM, BM=128 x BN=64, in-kernel fp32->fp16 via LDS.
// 1D grid of 324 with m204-bijective XCD swizzle (nwg=324, q=40, r=4):
// each XCD gets a contiguous ~40-item work chunk = one full (z, 4 rowt,
// 9 colt) window (X 4x98KB + W 9x49KB = 0.83 MB -> own-L2 resident), so
// panel re-reads become L2 hits instead of 8x L3 re-fetches.
// ---------------------------------------------------------------------------
__global__ __launch_bounds__(512) void qkv_lds_kernel(
    const float* __restrict__ X,
    const float* __restrict__ Wq, const float* __restrict__ Wk,
    const float* __restrict__ Wv,
    _Float16* __restrict__ PTQ, _Float16* __restrict__ PTK,
    _Float16* __restrict__ PTV)
{
    // bijective XCD swizzle: nwg=324, NXCD=8 -> q=40, r=4
    const int bid  = blockIdx.x;
    const int xcd  = bid & 7;
    const int idx  = bid >> 3;
    const int wgid = (xcd < 4) ? xcd * 41 + idx : 164 + (xcd - 4) * 40 + idx;

    const int colt = wgid % 9;
    const int rem  = wgid / 9;
    const int rowt = rem & 3;
    const int z    = rem >> 2;          // 0..8
    const int w    = z / 3;
    const int kc   = z - w * 3;

    const float* W = (w == 0) ? Wq : (w == 1) ? Wk : Wv;

    const int tid  = threadIdx.x;
    const int lane = tid & 63;
    const int wv   = tid >> 6;           // 0..7
    const int wr   = wv >> 1;            // 0..3
    const int wc   = wv & 1;             // 0..1
    const int brow0 = rowt * 128;
    const int bcol0 = colt * 64;
    const int kbase = kc * 192;

    __shared__ _Float16 LA[8 * 6 * 64 * 8];   // 48 KB  [fr][ks][slot][8]
    __shared__ _Float16 LB[4 * 6 * 64 * 8];   // 24 KB

#pragma unroll
    for (int it = 0; it < 6; ++it) {
        const int task = it * 512 + tid;
        const int r  = task / 24;
        const int kq = task - r * 24;
        const int k  = kq * 8;
        const int fr   = r >> 4;
        const int ks   = k >> 5;
        const int slot = ((r & 15) + 16 * ((k & 31) >> 3)) ^ ks;
        const float* s = X + (size_t)(brow0 + r) * DF + kbase + k;
        const float4 v0 = *reinterpret_cast<const float4*>(s);
        const float4 v1 = *reinterpret_cast<const float4*>(s + 4);
        f16x8 h = {(_Float16)v0.x, (_Float16)v0.y, (_Float16)v0.z, (_Float16)v0.w,
                   (_Float16)v1.x, (_Float16)v1.y, (_Float16)v1.z, (_Float16)v1.w};
        *reinterpret_cast<f16x8*>(&LA[((fr * 6 + ks) * 64 + slot) * 8]) = h;
    }
#pragma unroll
    for (int it = 0; it < 3; ++it) {
        const int task = it * 512 + tid;
        const int r  = task / 24;
        const int kq = task - r * 24;
        const int k  = kq * 8;
        const int fr   = r >> 4;
        const int ks   = k >> 5;
        const int slot = ((r & 15) + 16 * ((k & 31) >> 3)) ^ ks;
        const float* s = W + (size_t)(bcol0 + r) * DF + kbase + k;
        const float4 v0 = *reinterpret_cast<const float4*>(s);
        const float4 v1 = *reinterpret_cast<const float4*>(s + 4);
        f16x8 h = {(_Float16)v0.x, (_Float16)v0.y, (_Float16)v0.z, (_Float16)v0.w,
                   (_Float16)v1.x, (_Float16)v1.y, (_Float16)v1.z, (_Float16)v1.w};
        *reinterpret_cast<f16x8*>(&LB[((fr * 6 + ks) * 64 + slot) * 8]) = h;
    }
    __syncthreads();

    f32x4 acc[2][2] = {{{0.f,0.f,0.f,0.f},{0.f,0.f,0.f,0.f}},
                       {{0.f,0.f,0.f,0.f},{0.f,0.f,0.f,0.f}}};
#pragma unroll
    for (int half = 0; half < 2; ++half) {
        f16x8 fa[2][3], fb[2][3];
#pragma unroll
        for (int s = 0; s < 3; ++s) {
            const int ks = half * 3 + s;
            const int sl = (lane ^ ks) * 8;
#pragma unroll
            for (int mi = 0; mi < 2; ++mi)
                fa[mi][s] = *reinterpret_cast<const f16x8*>(
                    &LA[((wr * 2 + mi) * 6 + ks) * 512 + sl]);
#pragma unroll
            for (int ni = 0; ni < 2; ++ni)
                fb[ni][s] = *reinterpret_cast<const f16x8*>(
                    &LB[((wc * 2 + ni) * 6 + ks) * 512 + sl]);
        }
#pragma unroll
        for (int s = 0; s < 3; ++s) {
            acc[0][0] = __builtin_amdgcn_mfma_f32_16x16x32_f16(fa[0][s], fb[0][s], acc[0][0], 0, 0, 0);
            acc[0][1] = __builtin_amdgcn_mfma_f32_16x16x32_f16(fa[0][s], fb[1][s], acc[0][1], 0, 0, 0);
            acc[1][0] = __builtin_amdgcn_mfma_f32_16x16x32_f16(fa[1][s], fb[0][s], acc[1][0], 0, 0, 0);
            acc[1][1] = __builtin_amdgcn_mfma_f32_16x16x32_f16(fa[1][s], fb[1][s], acc[1][1], 0, 0, 0);
        }
    }

    const size_t pl = (size_t)NR * DF;
#pragma unroll
    for (int ni = 0; ni < 2; ++ni) {
        const int col = bcol0 + wc * 32 + ni * 16 + (lane & 15);
#pragma unroll
        for (int mi = 0; mi < 2; ++mi) {
            const int row0 = brow0 + wr * 32 + mi * 16 + (lane >> 4) * 4;
#pragma unroll
            for (int r = 0; r < 4; ++r) {
                const size_t idx2 = kc * pl + (size_t)(row0 + r) * DF + col;
                const float v = acc[mi][ni][r];
                if (w == 0)      PTQ[idx2] = (_Float16)v;
                else if (w == 1) PTK[idx2] = (_Float16)(v * LOG2E);
                else             PTV[idx2] = (_Float16)v;
            }
        }
    }
}

// ---------------------------------------------------------------------------
// Kernel 2: rank-1 attention via tilted-mean interpolation.
// 16 nodes x 36 chunks (576 = 16*36): 16 exps + 8 float4 LDS reads per
// thread in the build.  Fused 3-way split-K reduce (+bias), fp16 partials.
// Wave-parallel q min/max.
// ---------------------------------------------------------------------------
#define M_NODES 16
#define CHUNKS  36
#define JPC     16
#define CSTRIDE 9             // float4 units: 8 data + 1 pad

__global__ __launch_bounds__(576) void attn_interp_kernel(
    const _Float16* __restrict__ PTQ, const _Float16* __restrict__ PTK,
    const _Float16* __restrict__ PTV,
    const float* __restrict__ bq, const float* __restrict__ bk,
    const float* __restrict__ bv,
    float* __restrict__ out)
{
    const int n = blockIdx.x;
    const int t = threadIdx.x;
    const size_t nb = (size_t)n * DF + t;
    const size_t pl = (size_t)NR * DF;

    const float qv = ((float)PTQ[nb] + (float)PTQ[pl + nb] + (float)PTQ[pl * 2 + nb])
                     + bq[t];
    const float kl = ((float)PTK[nb] + (float)PTK[pl + nb] + (float)PTK[pl * 2 + nb])
                     + bk[t] * LOG2E;
    const float vv = ((float)PTV[nb] + (float)PTV[pl + nb] + (float)PTV[pl * 2 + nb])
                     + bv[t];

    __shared__ __align__(16) float4 KV4[CHUNKS * CSTRIDE];   // 5184 B
    __shared__ __align__(16) float Pf[DF];
    __shared__ __align__(16) float Pg[DF];
    __shared__ float Rt[M_NODES];
    __shared__ float Wmn[9], Wmx[9];

    {
        const int c  = t >> 4;            // chunk 0..35
        const int jl = t & 15;            // j within chunk
        float2* dst = reinterpret_cast<float2*>(&KV4[c * CSTRIDE + (jl >> 1)]);
        dst[jl & 1] = make_float2(kl, vv);
    }

    // wave-parallel min/max of q (9 waves in parallel, then LDS broadcast)
    {
        float lo = qv, hi = qv;
#pragma unroll
        for (int s = 32; s; s >>= 1) {
            lo = fminf(lo, __shfl_xor(lo, s, 64));
            hi = fmaxf(hi, __shfl_xor(hi, s, 64));
        }
        if ((t & 63) == 0) { Wmn[t >> 6] = lo; Wmx[t >> 6] = hi; }
    }
    __syncthreads();            // covers KV4 staging + Wmn/Wmx

    float qmin = Wmn[0], qmax = Wmx[0];
#pragma unroll
    for (int i = 1; i < 9; ++i) {
        qmin = fminf(qmin, Wmn[i]);
        qmax = fmaxf(qmax, Wmx[i]);
    }
    const float h   = fmaxf((qmax - qmin) * (1.0f / (M_NODES - 5)), 1e-6f);
    const float qlo = qmin - 2.0f * h;

    // build: thread = (node m, chunk c); 16 j's each
    const int m = t / CHUNKS;             // 0..15
    const int c = t - m * CHUNKS;         // 0..35
    const float qm = qlo + h * (float)m;
    const float4* kvp = KV4 + c * CSTRIDE;
    float f0 = 0.f, f1 = 0.f, g0 = 0.f, g1 = 0.f;
#pragma unroll
    for (int jj = 0; jj < JPC / 2; ++jj) {
        float4 p = kvp[jj];
        float e0 = EXP2F(qm * p.x);
        float e1 = EXP2F(qm * p.z);
        g0 += e0; g1 += e1;
        f0 = fmaf(e0, p.y, f0);
        f1 = fmaf(e1, p.w, f1);
    }
    Pf[t] = f0 + f1;
    Pg[t] = g0 + g1;
    __syncthreads();

    if (t < M_NODES) {                    // reduce 36 chunks -> R node
        const float4* pf4 = reinterpret_cast<const float4*>(Pf) + t * 9;
        const float4* pg4 = reinterpret_cast<const float4*>(Pg) + t * 9;
        float fs = 0.f, gs = 0.f;
#pragma unroll
        for (int i = 0; i < 9; ++i) {
            float4 a = pf4[i], b = pg4[i];
            fs += (a.x + a.y) + (a.z + a.w);
            gs += (b.x + b.y) + (b.z + b.w);
        }
        Rt[t] = fs / gs;
    }
    __syncthreads();

    const float u = (qv - qlo) * (1.0f / h);
    int i0 = (int)u;
    i0 = (i0 < 1) ? 1 : (i0 > M_NODES - 3 ? M_NODES - 3 : i0);
    const float tf = u - (float)i0;
    const float a  = Rt[i0 - 1];
    const float b  = Rt[i0];
    const float cc = Rt[i0 + 1];
    const float d  = Rt[i0 + 2];
    const float m0 = 0.5f * (cc - a);
    const float m1 = 0.5f * (d - b);
    const float dd = cc - b;
    const float r  = b + tf * (m0 + tf * ((3.f * dd - 2.f * m0 - m1)
                                          + tf * (m0 + m1 - 2.f * dd)));
    out[(size_t)n * DF + t] = r;
}

// ---------------------------------------------------------------------------
extern "C" void kernel_launch(void* const* d_in, const int* in_sizes, int n_in,
                              void* d_out, int out_size, void* d_ws, size_t ws_size,
                              hipStream_t stream) {
    const float* x  = (const float*)d_in[0];
    const float* Wq = (const float*)d_in[1];
    const float* bq = (const float*)d_in[2];
    const float* Wk = (const float*)d_in[3];
    const float* bk = (const float*)d_in[4];
    const float* Wv = (const float*)d_in[5];
    const float* bv = (const float*)d_in[6];

    char* ws = (char*)d_ws;
    _Float16* PTQ = (_Float16*)(ws + PTQ_OFF);
    _Float16* PTK = (_Float16*)(ws + PTK_OFF);
    _Float16* PTV = (_Float16*)(ws + PTV_OFF);

    qkv_lds_kernel<<<324, 512, 0, stream>>>(
        x, Wq, Wk, Wv, PTQ, PTK, PTV);

    attn_interp_kernel<<<NR, DF, 0, stream>>>(
        PTQ, PTK, PTV, bq, bk, bv, (float*)d_out);
}